// Round 3
// baseline (134.056 us; speedup 1.0000x reference)
//
#include <hip/hip_runtime.h>
#include <hip/hip_bf16.h>
#include <stdint.h>

// Problem constants (fixed by reference: N=M=16384, D=64, T=1)
#define N_ROWS 16384
#define D_DIM 64
#define NSPLIT 16                           // col splits per row-group
#define COLS_PER_SPLIT (N_ROWS / NSPLIT)    // 1024
#define N_ITER (COLS_PER_SPLIT / 64)        // 16 iters of 64 cols
#define SHIFT2 64.0f                        // LSE shift, log2 domain
#define LOG2E 1.44269504088896340736f
#define LN2 0.69314718055994530942f

using short8  = __attribute__((ext_vector_type(8))) short;
using float4v = __attribute__((ext_vector_type(4))) float;

// ---------- bf16 helpers ----------
__device__ __forceinline__ unsigned short f2bf(float f) {
  unsigned u = __float_as_uint(f);
  unsigned r = (u + 0x7fffu + ((u >> 16) & 1u)) >> 16;   // RNE
  return (unsigned short)r;
}
__device__ __forceinline__ float bf2f(unsigned short s) {
  return __uint_as_float(((unsigned)s) << 16);
}

// ---------- prep: q' = logits*log2e - log2(noise) -> bf16 ; targets -> bf16 ----------
// Also: zeroes row_sums/out, and computes diag[n] = sum_d q'_bf[n][d]*t_bf[n][d]
__global__ void prep_kernel(const float4* __restrict__ lg,
                            const float4* __restrict__ tg,
                            const float* __restrict__ noise,
                            ushort4* __restrict__ qa,
                            ushort4* __restrict__ tb,
                            float* __restrict__ row_sums,
                            float* __restrict__ diag,
                            float* __restrict__ out) {
  __shared__ float l2n[64];
  int tid = threadIdx.x;
  if (tid < 64) l2n[tid] = log2f(noise[tid]);
  __syncthreads();

  int i = blockIdx.x * blockDim.x + tid;    // 0 .. 262143 (1M floats / 4)
  if (i < N_ROWS) row_sums[i] = 0.f;
  if (i == 0) out[0] = 0.f;

  int d4 = (i & 15) << 2;                   // 16 float4 per 64-elem row
  float4 l = lg[i];
  float4 t = tg[i];
  ushort4 ua, ub;
  ua.x = f2bf(l.x * LOG2E - l2n[d4 + 0]);
  ua.y = f2bf(l.y * LOG2E - l2n[d4 + 1]);
  ua.z = f2bf(l.z * LOG2E - l2n[d4 + 2]);
  ua.w = f2bf(l.w * LOG2E - l2n[d4 + 3]);
  ub.x = f2bf(t.x);
  ub.y = f2bf(t.y);
  ub.z = f2bf(t.z);
  ub.w = f2bf(t.w);
  qa[i] = ua;
  tb[i] = ub;

  // diagonal partial: product of the bf16-rounded values (matches MFMA inputs)
  float part = bf2f(ua.x) * bf2f(ub.x) + bf2f(ua.y) * bf2f(ub.y) +
               bf2f(ua.z) * bf2f(ub.z) + bf2f(ua.w) * bf2f(ub.w);
  part += __shfl_xor(part, 1);
  part += __shfl_xor(part, 2);
  part += __shfl_xor(part, 4);
  part += __shfl_xor(part, 8);
  if ((tid & 15) == 0) diag[i >> 4] = part;   // 16 consecutive threads per row
}

// ---------- flash: per-row sum of 2^(s' - 64); no LDS, no barriers ----------
// Each wave owns 64 rows x 1024-col strip. A fragments loaded once from global;
// B fragments streamed from global (tb is 2 MB -> L2-resident).
__global__ __launch_bounds__(256, 4) void flash_kernel(
    const uint8_t* __restrict__ qa,   // bf16 [16384][64], pre-scaled by log2e
    const uint8_t* __restrict__ tb,   // bf16 [16384][64]
    float* __restrict__ row_sums) {   // [16384], pre-zeroed
  const int lane = threadIdx.x & 63;
  const int gwave = blockIdx.x * 4 + (threadIdx.x >> 6);  // 0..4095
  const int rg = gwave >> 4;          // row group 0..255 (64 rows each)
  const int sp = gwave & 15;          // col split 0..15  (1024 cols each)
  const int row0 = rg * 64;
  const int col0 = sp * COLS_PER_SPLIT;

  const int m = lane & 15;            // fragment row/col within 16
  const int kc = lane >> 4;           // k-chunk 0..3

  // A fragments: lane holds A[i*16+m][k2*32 + kc*8 .. +8] (16 B)
  short8 afrag[4][2];
#pragma unroll
  for (int i = 0; i < 4; ++i)
#pragma unroll
    for (int k2 = 0; k2 < 2; ++k2)
      afrag[i][k2] = *(const short8*)(qa + (size_t)(row0 + i * 16 + m) * 128 +
                                      (k2 * 4 + kc) * 16);

  float sums[4][4];
#pragma unroll
  for (int i = 0; i < 4; ++i)
#pragma unroll
    for (int r = 0; r < 4; ++r) sums[i][r] = 0.f;

  // per-lane invariant part of the B offset
  const uint8_t* bbase = tb + (size_t)(col0 + m) * 128 + kc * 16;

#pragma unroll 2
  for (int it = 0; it < N_ITER; ++it) {
    // load this iter's 64x64 B fragments (8 x 16 B per lane)
    short8 bfrag[4][2];
#pragma unroll
    for (int j = 0; j < 4; ++j)
#pragma unroll
      for (int k2 = 0; k2 < 2; ++k2)
        bfrag[j][k2] = *(const short8*)(bbase + it * 8192 + j * 2048 + k2 * 64);

#pragma unroll
    for (int j = 0; j < 4; ++j) {
      float4v acc[4];
#pragma unroll
      for (int i = 0; i < 4; ++i) {
        float4v a0 = {-SHIFT2, -SHIFT2, -SHIFT2, -SHIFT2};
        a0 = __builtin_amdgcn_mfma_f32_16x16x32_bf16(afrag[i][0], bfrag[j][0], a0, 0, 0, 0);
        a0 = __builtin_amdgcn_mfma_f32_16x16x32_bf16(afrag[i][1], bfrag[j][1], a0, 0, 0, 0);
        acc[i] = a0;
      }
      // C layout: col = lane&15, row = kc*4 + r
#pragma unroll
      for (int i = 0; i < 4; ++i)
#pragma unroll
        for (int r = 0; r < 4; ++r)
          sums[i][r] += __builtin_amdgcn_exp2f(acc[i][r]);
    }
  }

  // reduce over the 16 column-lanes holding the same row
#pragma unroll
  for (int i = 0; i < 4; ++i)
#pragma unroll
    for (int r = 0; r < 4; ++r) {
      float v = sums[i][r];
      v += __shfl_xor(v, 1);
      v += __shfl_xor(v, 2);
      v += __shfl_xor(v, 4);
      v += __shfl_xor(v, 8);
      if (m == 0) {
        int grow = row0 + i * 16 + kc * 4 + r;
        atomicAdd(&row_sums[grow], v);
      }
    }
}

// ---------- finish: loss_n = ln2*(64 + log2(sum_n) - diag_n); mean over n ----------
__global__ void finish_kernel(const float* __restrict__ row_sums,
                              const float* __restrict__ diag,
                              float* __restrict__ out) {
  int n = blockIdx.x * blockDim.x + threadIdx.x;   // 0..16383
  float loss = LN2 * (SHIFT2 + log2f(row_sums[n]) - diag[n]);
#pragma unroll
  for (int off = 32; off; off >>= 1) loss += __shfl_down(loss, off);
  if ((threadIdx.x & 63) == 0) atomicAdd(out, loss * (1.0f / N_ROWS));
}

extern "C" void kernel_launch(void* const* d_in, const int* in_sizes, int n_in,
                              void* d_out, int out_size, void* d_ws, size_t ws_size,
                              hipStream_t stream) {
  const float* logits  = (const float*)d_in[0];   // [16384][64] fp32
  const float* targets = (const float*)d_in[1];   // [16384][64] fp32
  const float* noise   = (const float*)d_in[2];   // [64] fp32
  float* out = (float*)d_out;

  uint8_t* ws = (uint8_t*)d_ws;
  uint8_t* qa = ws;                                  // bf16 q', 2 MB
  uint8_t* tb = ws + (size_t)2 * 1024 * 1024;        // bf16 targets, 2 MB
  float* row_sums = (float*)(ws + (size_t)4 * 1024 * 1024);            // 64 KB
  float* diag     = (float*)(ws + (size_t)4 * 1024 * 1024 + 65536);    // 64 KB

  prep_kernel<<<1024, 256, 0, stream>>>(
      (const float4*)logits, (const float4*)targets, noise,
      (ushort4*)qa, (ushort4*)tb, row_sums, diag, out);

  flash_kernel<<<(256 * NSPLIT) / 4, 256, 0, stream>>>(qa, tb, row_sums);

  finish_kernel<<<N_ROWS / 256, 256, 0, stream>>>(row_sums, diag, out);
}